// Round 3
// baseline (806.084 us; speedup 1.0000x reference)
//
#include <hip/hip_runtime.h>

#define C_   192
#define N_   32
#define H_   112
#define W_   112
#define V_   4                  // output rows per thread
#define HT   (H_ / V_)          // 28 row-tiles per plane
#define NC   (N_ * C_)          // 6144 planes
#define NRT  (NC * HT)          // 172032 row-strips total
#define BLK  256
#define HWPB (BLK / 32)         // 8 half-wave row-strips per block
#define NBLK (NRT / HWPB)       // 21504 blocks, exact

typedef float vf4 __attribute__((ext_vector_type(4)));

// Zero the per-channel sum/sumsq accumulators (ws is poisoned 0xAA each call).
__global__ void zero_acc_kernel(float* __restrict__ acc) {
    for (int i = threadIdx.x; i < 2 * C_; i += blockDim.x) acc[i] = 0.0f;
}

struct Row { float l; float4 m; float r; };

// One 16B row segment; halo elements come from neighbor lanes via shuffle.
// Half-wave (32 lanes) covers one row: lane j-1 holds the float4 to our left.
// Lane masks (has_l/has_r) also kill the 31<->32 half-wave seam leakage.
__device__ __forceinline__ Row load_row_sh(const float* __restrict__ p,
                                           bool has_l, bool has_r) {
    Row r;
    r.m = *(const float4*)p;
    const float lv = __shfl_up(r.m.w, 1, 64);
    const float rv = __shfl_down(r.m.x, 1, 64);
    r.l = has_l ? lv : 0.0f;
    r.r = has_r ? rv : 0.0f;
    return r;
}

__device__ __forceinline__ void fma_row(const Row& r, float w0, float w1, float w2,
                                        float4& a) {
    a.x += w0 * r.l   + w1 * r.m.x + w2 * r.m.y;
    a.y += w0 * r.m.x + w1 * r.m.y + w2 * r.m.z;
    a.z += w0 * r.m.y + w1 * r.m.z + w2 * r.m.w;
    a.w += w0 * r.m.z + w1 * r.m.w + w2 * r.r;
}

// 3x3 depthwise conv (bias cancels in BN), zero padding.
// V_ x 4 output tile; 6 unconditional dwordx4 loads, halos via shuffle.
// Halo rows at ht boundaries: clamped (safe) address, result zeroed by cndmask.
__device__ __forceinline__ void conv_tile(const float* __restrict__ plane,
                                          int ht, int jeff, bool hl, bool hr,
                                          const float* wc, float4 y[V_]) {
    const float* rp = plane + (size_t)(ht * V_) * W_ + 4 * jeff;
    Row rows[V_ + 2];
    {
        const float* p = (ht > 0) ? (rp - W_) : rp;
        Row r = load_row_sh(p, hl, hr);
        if (ht == 0) { r.l = 0.f; r.m = make_float4(0.f, 0.f, 0.f, 0.f); r.r = 0.f; }
        rows[0] = r;
    }
#pragma unroll
    for (int v = 0; v < V_; ++v)
        rows[1 + v] = load_row_sh(rp + v * W_, hl, hr);
    {
        const float* p = (ht < HT - 1) ? (rp + V_ * W_) : rp;
        Row r = load_row_sh(p, hl, hr);
        if (ht == HT - 1) { r.l = 0.f; r.m = make_float4(0.f, 0.f, 0.f, 0.f); r.r = 0.f; }
        rows[V_ + 1] = r;
    }
#pragma unroll
    for (int v = 0; v < V_; ++v) {
        float4 a = {0.f, 0.f, 0.f, 0.f};
        fma_row(rows[v],     wc[0], wc[1], wc[2], a);
        fma_row(rows[v + 1], wc[3], wc[4], wc[5], a);
        fma_row(rows[v + 2], wc[6], wc[7], wc[8], a);
        y[v] = a;
    }
}

// Pass 1: per-channel sum and sum-of-squares of the (biasless) conv output.
// Reduction is PER HALF-WAVE: each 32-lane group owns one (nc, ht) strip, so
// its channel is uniform. (A block can straddle plane boundaries — 28 strips
// per plane vs 8 per block — so a block-wide reduction would mix channels.)
__global__ __launch_bounds__(BLK, 4) void stats_kernel(const float* __restrict__ in,
                                                       const float* __restrict__ w,
                                                       float* __restrict__ acc) {
    const int tid  = threadIdx.x;
    const int R    = blockIdx.x * HWPB + (tid >> 5);   // row-strip (nc, ht)
    const int j    = tid & 31;
    const bool act = (j < 28);
    const int jeff = act ? j : 27;                     // clamp idle lanes (safe addr)
    const int nc   = R / HT;
    const int ht   = R - nc * HT;
    const int c    = nc % C_;

    float wc[9];
#pragma unroll
    for (int k = 0; k < 9; ++k) wc[k] = w[c * 9 + k];

    const float* plane = in + (size_t)nc * (H_ * W_);
    float4 y[V_];
    conv_tile(plane, ht, jeff, j > 0, j < 27, wc, y);   // all lanes: shuffles need them

    float s = 0.0f, ss = 0.0f;
    if (act) {
#pragma unroll
        for (int v = 0; v < V_; ++v) {
            s  += (y[v].x + y[v].y) + (y[v].z + y[v].w);
            ss += (y[v].x * y[v].x + y[v].y * y[v].y)
                + (y[v].z * y[v].z + y[v].w * y[v].w);
        }
    }

    // half-wave (32-lane) reduction; c is uniform within the half-wave
#pragma unroll
    for (int off = 16; off > 0; off >>= 1) {
        s  += __shfl_down(s,  off, 32);
        ss += __shfl_down(ss, off, 32);
    }
    if (j == 0) {
        atomicAdd(&acc[c],      s);
        atomicAdd(&acc[C_ + c], ss);
    }
}

// Pass 1.5: fold stats + gamma/beta into per-channel scale/shift.
__global__ void finalize_kernel(const float* __restrict__ acc,
                                const float* __restrict__ gamma,
                                const float* __restrict__ beta,
                                float* __restrict__ st) {
    const int c = threadIdx.x;
    if (c < C_) {
        const float M    = (float)N_ * (float)H_ * (float)W_;
        const float mean = acc[c] / M;
        float var        = acc[C_ + c] / M - mean * mean;
        var              = fmaxf(var, 0.0f);
        const float sc   = gamma[c] * rsqrtf(var + 1e-5f);
        st[c]       = sc;
        st[C_ + c]  = beta[c] - sc * mean;   // conv bias b cancels algebraically
    }
}

// Pass 2: recompute conv, apply scale/shift + ReLU6, store V_ rows.
// Blocks run in REVERSE so reads hit LLC data still warm from the stats pass;
// output stores are non-temporal so they don't evict the input stream.
__global__ __launch_bounds__(BLK, 4) void apply_kernel(const float* __restrict__ in,
                                                       const float* __restrict__ w,
                                                       const float* __restrict__ st,
                                                       float* __restrict__ out) {
    const int tid  = threadIdx.x;
    const int bid  = (int)gridDim.x - 1 - (int)blockIdx.x;   // reversed traversal
    const int R    = bid * HWPB + (tid >> 5);
    const int j    = tid & 31;
    const bool act = (j < 28);
    const int jeff = act ? j : 27;
    const int nc   = R / HT;
    const int ht   = R - nc * HT;
    const int c    = nc % C_;

    float wc[9];
#pragma unroll
    for (int k = 0; k < 9; ++k) wc[k] = w[c * 9 + k];
    const float sc = st[c];
    const float sh = st[C_ + c];

    const float* plane = in + (size_t)nc * (H_ * W_);
    float4 y[V_];
    conv_tile(plane, ht, jeff, j > 0, j < 27, wc, y);   // all lanes participate

    if (act) {
        float* orow = out + (size_t)nc * (H_ * W_) + (size_t)(ht * V_) * W_ + 4 * j;
#pragma unroll
        for (int v = 0; v < V_; ++v) {
            float4 z;
            z.x = fminf(fmaxf(sc * y[v].x + sh, 0.0f), 6.0f);
            z.y = fminf(fmaxf(sc * y[v].y + sh, 0.0f), 6.0f);
            z.z = fminf(fmaxf(sc * y[v].z + sh, 0.0f), 6.0f);
            z.w = fminf(fmaxf(sc * y[v].w + sh, 0.0f), 6.0f);
            __builtin_nontemporal_store(*(vf4*)&z, (vf4*)(orow + (size_t)v * W_));
        }
    }
}

extern "C" void kernel_launch(void* const* d_in, const int* in_sizes, int n_in,
                              void* d_out, int out_size, void* d_ws, size_t ws_size,
                              hipStream_t stream) {
    const float* in    = (const float*)d_in[0];
    const float* w     = (const float*)d_in[1];
    // d_in[2] = conv bias b: unused — cancels exactly inside training-mode BN.
    const float* gamma = (const float*)d_in[3];
    const float* beta  = (const float*)d_in[4];
    float* out = (float*)d_out;

    float* acc = (float*)d_ws;      // [0, 2C): sum, sumsq
    float* st  = acc + 2 * C_;      // [2C, 4C): scale, shift

    hipLaunchKernelGGL(zero_acc_kernel, dim3(1), dim3(64), 0, stream, acc);
    hipLaunchKernelGGL(stats_kernel, dim3(NBLK), dim3(BLK), 0, stream, in, w, acc);
    hipLaunchKernelGGL(finalize_kernel, dim3(1), dim3(C_), 0, stream,
                       acc, gamma, beta, st);
    hipLaunchKernelGGL(apply_kernel, dim3(NBLK), dim3(BLK), 0, stream, in, w, st, out);
}

// Round 4
// 584.434 us; speedup vs baseline: 1.3793x; 1.3793x over previous
//
#include <hip/hip_runtime.h>

#define C_    192
#define N_    32
#define H_    112
#define W_    112
#define V_    4                 // output rows per strip
#define HT    28                // strips per plane (112/4)
#define KB    16                // blocks per channel
#define ITERS 7                 // strips per half-wave: KB*8*ITERS = 896 = 32*28
#define BLK   256
#define NBLK  (C_ * KB)         // 3072 blocks per pass

// Zero the per-channel sum/sumsq accumulators (ws is poisoned 0xAA each call).
__global__ void zero_acc_kernel(float* __restrict__ acc) {
    for (int i = threadIdx.x; i < 2 * C_; i += blockDim.x) acc[i] = 0.0f;
}

__device__ __forceinline__ float4 ldg4(const float* __restrict__ p) {
    return *(const float4*)p;
}

// select-zero a float4 (no divergent branch)
__device__ __forceinline__ float4 selz(float4 v, bool zero) {
    float4 r;
    r.x = zero ? 0.f : v.x;  r.y = zero ? 0.f : v.y;
    r.z = zero ? 0.f : v.z;  r.w = zero ? 0.f : v.w;
    return r;
}

// Load the 6 input rows (16B each) for strip q of this block's channel chunk.
// Top/bottom halo rows use a clamped (safe) address; zeroed at compute time.
template <typename T>
__device__ __forceinline__ void load_strip(const float* __restrict__ in,
                                           int c, int k, int q, int jeff,
                                           T r[6]) {
    const int n  = 2 * k + (q >= HT ? 1 : 0);
    const int ht = q - (q >= HT ? HT : 0);
    const float* plane = in + (size_t)(n * C_ + c) * (H_ * W_);
    const float* rp    = plane + (size_t)(ht * V_) * W_ + 4 * jeff;
    r[0] = ldg4(ht > 0 ? rp - W_ : rp);      // zeroed later if ht==0
    r[1] = ldg4(rp);
    r[2] = ldg4(rp + W_);
    r[3] = ldg4(rp + 2 * W_);
    r[4] = ldg4(rp + 3 * W_);
    r[5] = ldg4(ht < HT - 1 ? rp + 4 * W_ : rp);   // zeroed later if ht==HT-1
}

// 3x3 depthwise conv on a loaded 6-row strip; halos via half-wave shuffles.
__device__ __forceinline__ void conv_strip(float4 r[6], int q, int j,
                                           const float* wc, float4 y[V_]) {
    const int ht = q - (q >= HT ? HT : 0);
    r[0] = selz(r[0], ht == 0);
    r[5] = selz(r[5], ht == HT - 1);
    float l[6], rr[6];
#pragma unroll
    for (int t = 0; t < 6; ++t) {
        l[t]  = __shfl_up(r[t].w, 1, 64);
        rr[t] = __shfl_down(r[t].x, 1, 64);
        l[t]  = (j > 0)  ? l[t]  : 0.0f;
        rr[t] = (j < 27) ? rr[t] : 0.0f;
    }
#pragma unroll
    for (int v = 0; v < V_; ++v) {
        float4 a = {0.f, 0.f, 0.f, 0.f};
#pragma unroll
        for (int t = 0; t < 3; ++t) {      // vertical taps
            const float4 m = r[v + t];
            const float w0 = wc[3 * t], w1 = wc[3 * t + 1], w2 = wc[3 * t + 2];
            a.x += w0 * l[v + t] + w1 * m.x + w2 * m.y;
            a.y += w0 * m.x      + w1 * m.y + w2 * m.z;
            a.z += w0 * m.y      + w1 * m.z + w2 * m.w;
            a.w += w0 * m.z      + w1 * m.w + w2 * rr[v + t];
        }
        y[v] = a;
    }
}

// Pass 1: per-channel sum/sumsq. Block = one channel chunk (2 planes, 56 strips);
// each half-wave pipelines 7 strips with next-strip register prefetch.
__global__ __launch_bounds__(BLK, 4) void stats_kernel(const float* __restrict__ in,
                                                       const float* __restrict__ w,
                                                       float* __restrict__ acc) {
    const int tid  = threadIdx.x;
    const int h    = tid >> 5;          // half-wave 0..7
    const int j    = tid & 31;
    const bool act = (j < 28);
    const int jeff = act ? j : 27;
    const int c    = blockIdx.x >> 4;   // channel (uniform per block)
    const int k    = blockIdx.x & 15;   // chunk within channel

    float wc[9];
#pragma unroll
    for (int t = 0; t < 9; ++t) wc[t] = w[c * 9 + t];

    float s = 0.0f, ss = 0.0f;
    float4 cur[6], nxt[6];
    load_strip(in, c, k, h, jeff, cur);
#pragma unroll
    for (int i = 0; i < ITERS; ++i) {
        if (i < ITERS - 1)
            load_strip(in, c, k, (i + 1) * 8 + h, jeff, nxt);   // prefetch
        float4 y[V_];
        conv_strip(cur, i * 8 + h, j, wc, y);
        if (act) {
#pragma unroll
            for (int v = 0; v < V_; ++v) {
                s  += (y[v].x + y[v].y) + (y[v].z + y[v].w);
                ss += (y[v].x * y[v].x + y[v].y * y[v].y)
                    + (y[v].z * y[v].z + y[v].w * y[v].w);
            }
        }
        if (i < ITERS - 1) {
#pragma unroll
            for (int t = 0; t < 6; ++t) cur[t] = nxt[t];
        }
    }

    // whole block is one channel: full-wave reduce, LDS across 4 waves, 2 atomics
#pragma unroll
    for (int off = 32; off > 0; off >>= 1) {
        s  += __shfl_down(s,  off, 64);
        ss += __shfl_down(ss, off, 64);
    }
    __shared__ float ls[BLK / 64], lss[BLK / 64];
    const int wv = tid >> 6;
    if ((tid & 63) == 0) { ls[wv] = s; lss[wv] = ss; }
    __syncthreads();
    if (tid == 0) {
        float S = 0.f, SS = 0.f;
#pragma unroll
        for (int t = 0; t < BLK / 64; ++t) { S += ls[t]; SS += lss[t]; }
        atomicAdd(&acc[c],      S);
        atomicAdd(&acc[C_ + c], SS);
    }
}

// Pass 1.5: fold stats + gamma/beta into per-channel scale/shift.
__global__ void finalize_kernel(const float* __restrict__ acc,
                                const float* __restrict__ gamma,
                                const float* __restrict__ beta,
                                float* __restrict__ st) {
    const int c = threadIdx.x;
    if (c < C_) {
        const float M    = (float)N_ * (float)H_ * (float)W_;
        const float mean = acc[c] / M;
        float var        = acc[C_ + c] / M - mean * mean;
        var              = fmaxf(var, 0.0f);
        const float sc   = gamma[c] * rsqrtf(var + 1e-5f);
        st[c]       = sc;
        st[C_ + c]  = beta[c] - sc * mean;   // conv bias b cancels algebraically
    }
}

// Pass 2: recompute conv, scale/shift + ReLU6, store. Same pipelined structure.
__global__ __launch_bounds__(BLK, 4) void apply_kernel(const float* __restrict__ in,
                                                       const float* __restrict__ w,
                                                       const float* __restrict__ st,
                                                       float* __restrict__ out) {
    const int tid  = threadIdx.x;
    const int h    = tid >> 5;
    const int j    = tid & 31;
    const bool act = (j < 28);
    const int jeff = act ? j : 27;
    const int c    = blockIdx.x >> 4;
    const int k    = blockIdx.x & 15;

    float wc[9];
#pragma unroll
    for (int t = 0; t < 9; ++t) wc[t] = w[c * 9 + t];
    const float sc = st[c];
    const float sh = st[C_ + c];

    float4 cur[6], nxt[6];
    load_strip(in, c, k, h, jeff, cur);
#pragma unroll
    for (int i = 0; i < ITERS; ++i) {
        if (i < ITERS - 1)
            load_strip(in, c, k, (i + 1) * 8 + h, jeff, nxt);   // prefetch
        const int q  = i * 8 + h;
        float4 y[V_];
        conv_strip(cur, q, j, wc, y);
        if (act) {
            const int n  = 2 * k + (q >= HT ? 1 : 0);
            const int ht = q - (q >= HT ? HT : 0);
            float* orow = out + (size_t)(n * C_ + c) * (H_ * W_)
                              + (size_t)(ht * V_) * W_ + 4 * j;
#pragma unroll
            for (int v = 0; v < V_; ++v) {
                float4 z;
                z.x = fminf(fmaxf(sc * y[v].x + sh, 0.0f), 6.0f);
                z.y = fminf(fmaxf(sc * y[v].y + sh, 0.0f), 6.0f);
                z.z = fminf(fmaxf(sc * y[v].z + sh, 0.0f), 6.0f);
                z.w = fminf(fmaxf(sc * y[v].w + sh, 0.0f), 6.0f);
                *(float4*)(orow + (size_t)v * W_) = z;
            }
        }
        if (i < ITERS - 1) {
#pragma unroll
            for (int t = 0; t < 6; ++t) cur[t] = nxt[t];
        }
    }
}

extern "C" void kernel_launch(void* const* d_in, const int* in_sizes, int n_in,
                              void* d_out, int out_size, void* d_ws, size_t ws_size,
                              hipStream_t stream) {
    const float* in    = (const float*)d_in[0];
    const float* w     = (const float*)d_in[1];
    // d_in[2] = conv bias b: unused — cancels exactly inside training-mode BN.
    const float* gamma = (const float*)d_in[3];
    const float* beta  = (const float*)d_in[4];
    float* out = (float*)d_out;

    float* acc = (float*)d_ws;      // [0, 2C): sum, sumsq
    float* st  = acc + 2 * C_;      // [2C, 4C): scale, shift

    hipLaunchKernelGGL(zero_acc_kernel, dim3(1), dim3(64), 0, stream, acc);
    hipLaunchKernelGGL(stats_kernel, dim3(NBLK), dim3(BLK), 0, stream, in, w, acc);
    hipLaunchKernelGGL(finalize_kernel, dim3(1), dim3(C_), 0, stream,
                       acc, gamma, beta, st);
    hipLaunchKernelGGL(apply_kernel, dim3(NBLK), dim3(BLK), 0, stream, in, w, st, out);
}